// Round 1
// baseline (276.397 us; speedup 1.0000x reference)
//
#include <hip/hip_runtime.h>

typedef __attribute__((ext_vector_type(8))) short short8;
typedef __attribute__((ext_vector_type(4))) float f32x4;

__device__ __forceinline__ float bf2f(unsigned short u) {
    union { unsigned int i; float f; } v; v.i = ((unsigned int)u) << 16; return v.f;
}
__device__ __forceinline__ unsigned short f2bf(float f) {
    union { float f; unsigned int i; } v; v.f = f;
    unsigned int r = v.i + 0x7fffu + ((v.i >> 16) & 1u);  // RNE
    return (unsigned short)(r >> 16);
}

#define BM 128
#define BN 128
#define BK 32
#define LDP 40  // LDS row pitch in shorts (32 + 8 pad; 80B, 16B-aligned)

// C[m][n] = sum_k A[m][k] * B[k][n] + bias[n], A staged to bf16, MFMA accumulate f32.
// If lang != nullptr, B/bias are per-language stacked; language from row-batch (512 rows/batch).
template<int A_BF16>
__global__ __launch_bounds__(256) void gemm_bias(
    const void* __restrict__ Av, const float* __restrict__ Bg,
    const float* __restrict__ biasg, float* __restrict__ C,
    int M, int N, int K,
    const int* __restrict__ lang, long Bstride, int biasStride)
{
    __shared__ __align__(16) unsigned short As[BM][LDP];
    __shared__ __align__(16) unsigned short Bs[BN][LDP];   // transposed: [n][k]

    const int t = threadIdx.x;
    const int gm0 = blockIdx.y * BM;
    const int gn0 = blockIdx.x * BN;

    const float* B = Bg;
    const float* bias = biasg;
    if (lang) {
        const int l = lang[gm0 >> 9];
        B += (long)l * Bstride;
        bias += (long)l * biasStride;
    }

    const int lane = t & 63;
    const int w = t >> 6;
    const int wm = w >> 1;          // 2x2 wave grid, each wave owns 64x64
    const int wn = w & 1;
    const int fr = lane & 15;
    const int kb = (lane >> 4) * 8;

    f32x4 acc[4][4];
#pragma unroll
    for (int m = 0; m < 4; ++m)
#pragma unroll
        for (int n = 0; n < 4; ++n)
            acc[m][n] = (f32x4){0.f, 0.f, 0.f, 0.f};

    const int arow = t >> 1, acol = (t & 1) * 16;   // A stage: 128 rows x 32 k
    const int brow = t >> 3, bcol = (t & 7) * 16;   // B stage: 32 k x 128 n

    for (int k0 = 0; k0 < K; k0 += BK) {
        // ---- stage A tile [BM][BK] ----
        if (A_BF16) {
            const unsigned short* Ap = (const unsigned short*)Av + (size_t)(gm0 + arow) * K + k0 + acol;
            *(short8*)&As[arow][acol]     = *(const short8*)(Ap);
            *(short8*)&As[arow][acol + 8] = *(const short8*)(Ap + 8);
        } else {
            const float* Ap = (const float*)Av + (size_t)(gm0 + arow) * K + k0 + acol;
            const float4* Ap4 = (const float4*)Ap;
            float4 a0 = Ap4[0], a1 = Ap4[1], a2 = Ap4[2], a3 = Ap4[3];
            short8 p0, p1;
            p0[0] = (short)f2bf(a0.x); p0[1] = (short)f2bf(a0.y);
            p0[2] = (short)f2bf(a0.z); p0[3] = (short)f2bf(a0.w);
            p0[4] = (short)f2bf(a1.x); p0[5] = (short)f2bf(a1.y);
            p0[6] = (short)f2bf(a1.z); p0[7] = (short)f2bf(a1.w);
            p1[0] = (short)f2bf(a2.x); p1[1] = (short)f2bf(a2.y);
            p1[2] = (short)f2bf(a2.z); p1[3] = (short)f2bf(a2.w);
            p1[4] = (short)f2bf(a3.x); p1[5] = (short)f2bf(a3.y);
            p1[6] = (short)f2bf(a3.z); p1[7] = (short)f2bf(a3.w);
            *(short8*)&As[arow][acol]     = p0;
            *(short8*)&As[arow][acol + 8] = p1;
        }
        // ---- stage B tile [BK][BN], scatter-transposed into Bs[n][k] ----
        {
            const float* Bp = B + (size_t)(k0 + brow) * N + gn0 + bcol;
            const float4* Bp4 = (const float4*)Bp;
            float4 b0 = Bp4[0], b1 = Bp4[1], b2 = Bp4[2], b3 = Bp4[3];
            Bs[bcol + 0][brow]  = f2bf(b0.x);
            Bs[bcol + 1][brow]  = f2bf(b0.y);
            Bs[bcol + 2][brow]  = f2bf(b0.z);
            Bs[bcol + 3][brow]  = f2bf(b0.w);
            Bs[bcol + 4][brow]  = f2bf(b1.x);
            Bs[bcol + 5][brow]  = f2bf(b1.y);
            Bs[bcol + 6][brow]  = f2bf(b1.z);
            Bs[bcol + 7][brow]  = f2bf(b1.w);
            Bs[bcol + 8][brow]  = f2bf(b2.x);
            Bs[bcol + 9][brow]  = f2bf(b2.y);
            Bs[bcol + 10][brow] = f2bf(b2.z);
            Bs[bcol + 11][brow] = f2bf(b2.w);
            Bs[bcol + 12][brow] = f2bf(b3.x);
            Bs[bcol + 13][brow] = f2bf(b3.y);
            Bs[bcol + 14][brow] = f2bf(b3.z);
            Bs[bcol + 15][brow] = f2bf(b3.w);
        }
        __syncthreads();

        short8 af[4], bfv[4];
#pragma unroll
        for (int m = 0; m < 4; ++m) af[m]  = *(const short8*)&As[wm * 64 + m * 16 + fr][kb];
#pragma unroll
        for (int n = 0; n < 4; ++n) bfv[n] = *(const short8*)&Bs[wn * 64 + n * 16 + fr][kb];
#pragma unroll
        for (int m = 0; m < 4; ++m)
#pragma unroll
            for (int n = 0; n < 4; ++n)
                acc[m][n] = __builtin_amdgcn_mfma_f32_16x16x32_bf16(af[m], bfv[n], acc[m][n], 0, 0, 0);
        __syncthreads();
    }

    // epilogue: D mapping col=lane&15, row=(lane>>4)*4+reg
    const int fq = lane >> 4;
#pragma unroll
    for (int n = 0; n < 4; ++n) {
        const int col = gn0 + wn * 64 + n * 16 + fr;
        const float bv = bias[col];
#pragma unroll
        for (int m = 0; m < 4; ++m) {
            const int row0 = gm0 + wm * 64 + m * 16 + fq * 4;
#pragma unroll
            for (int r = 0; r < 4; ++r) {
                C[(size_t)(row0 + r) * N + col] = acc[m][n][r] + bv;
            }
        }
    }
}

// Row LayerNorm (H=1024) + ReLU. Optionally writes f32 (in-place ok) and/or bf16.
__global__ __launch_bounds__(256) void ln_relu(
    const float* __restrict__ in, float* __restrict__ outf,
    unsigned short* __restrict__ outb, int bpitch, int bcol,
    const float* __restrict__ gammag, const float* __restrict__ betag,
    const int* __restrict__ lang)
{
    const int r = blockIdx.x, t = threadIdx.x;
    const float4 v = ((const float4*)(in + (size_t)r * 1024))[t];
    float s1 = v.x + v.y + v.z + v.w;
    float s2 = v.x * v.x + v.y * v.y + v.z * v.z + v.w * v.w;
#pragma unroll
    for (int off = 32; off > 0; off >>= 1) {
        s1 += __shfl_down(s1, off);
        s2 += __shfl_down(s2, off);
    }
    __shared__ float red[8];
    const int wid = t >> 6;
    if ((t & 63) == 0) { red[wid] = s1; red[4 + wid] = s2; }
    __syncthreads();
    s1 = red[0] + red[1] + red[2] + red[3];
    s2 = red[4] + red[5] + red[6] + red[7];
    const float mean = s1 * (1.0f / 1024.0f);
    const float var = fmaxf(s2 * (1.0f / 1024.0f) - mean * mean, 0.0f);
    const float rstd = rsqrtf(var + 1e-5f);
    const float* G = gammag;
    const float* Be = betag;
    if (lang) { const int l = lang[r >> 9]; G += l * 1024; Be += l * 1024; }
    const float4 g  = ((const float4*)G)[t];
    const float4 be = ((const float4*)Be)[t];
    float4 o;
    o.x = fmaxf((v.x - mean) * rstd * g.x + be.x, 0.0f);
    o.y = fmaxf((v.y - mean) * rstd * g.y + be.y, 0.0f);
    o.z = fmaxf((v.z - mean) * rstd * g.z + be.z, 0.0f);
    o.w = fmaxf((v.w - mean) * rstd * g.w + be.w, 0.0f);
    if (outf) ((float4*)(outf + (size_t)r * 1024))[t] = o;
    if (outb) {
        ushort4 h;
        h.x = f2bf(o.x); h.y = f2bf(o.y); h.z = f2bf(o.z); h.w = f2bf(o.w);
        *(ushort4*)(outb + (size_t)r * bpitch + bcol + t * 4) = h;
    }
}

// Per row: g = sigmoid(h . Wg2[l] + bg2[l]); scale ner half by g0, topic half by g1 (in-place on out).
__global__ __launch_bounds__(256) void gate_scale(
    const unsigned short* __restrict__ h,
    const float* __restrict__ Wg2, const float* __restrict__ bg2,
    const int* __restrict__ lang, float* __restrict__ out)
{
    const int r = blockIdx.x, t = threadIdx.x;
    const int l = lang[r >> 9];
    const ushort4 hv = *(const ushort4*)(h + (size_t)r * 1024 + t * 4);
    const float4* W = (const float4*)(Wg2 + (size_t)l * 2048);
    const float4 wa = W[t * 2], wb = W[t * 2 + 1];
    const float h0 = bf2f(hv.x), h1 = bf2f(hv.y), h2 = bf2f(hv.z), h3 = bf2f(hv.w);
    float d0 = h0 * wa.x + h1 * wa.z + h2 * wb.x + h3 * wb.z;
    float d1 = h0 * wa.y + h1 * wa.w + h2 * wb.y + h3 * wb.w;
#pragma unroll
    for (int off = 32; off > 0; off >>= 1) {
        d0 += __shfl_down(d0, off);
        d1 += __shfl_down(d1, off);
    }
    __shared__ float red[8];
    const int wid = t >> 6;
    if ((t & 63) == 0) { red[wid] = d0; red[4 + wid] = d1; }
    __syncthreads();
    d0 = red[0] + red[1] + red[2] + red[3] + bg2[l * 2 + 0];
    d1 = red[4] + red[5] + red[6] + red[7] + bg2[l * 2 + 1];
    const float g0 = 1.0f / (1.0f + __expf(-d0));
    const float g1 = 1.0f / (1.0f + __expf(-d1));
    float4* pn = (float4*)(out + (size_t)r * 1024);
    float4 a = pn[t];
    a.x *= g0; a.y *= g0; a.z *= g0; a.w *= g0;
    pn[t] = a;
    float4* pt = (float4*)(out + 8388608ull + (size_t)r * 1024);
    float4 b = pt[t];
    b.x *= g1; b.y *= g1; b.z *= g1; b.w *= g1;
    pt[t] = b;
}

extern "C" void kernel_launch(void* const* d_in, const int* in_sizes, int n_in,
                              void* d_out, int out_size, void* d_ws, size_t ws_size,
                              hipStream_t stream)
{
    const float* ner    = (const float*)d_in[0];
    const float* top    = (const float*)d_in[1];
    const int*   lang   = (const int*)d_in[2];
    const float* W_ner  = (const float*)d_in[3];
    const float* b_ner  = (const float*)d_in[4];
    const float* g_ner  = (const float*)d_in[5];
    const float* be_ner = (const float*)d_in[6];
    const float* W_top  = (const float*)d_in[7];
    const float* b_top  = (const float*)d_in[8];
    const float* g_top  = (const float*)d_in[9];
    const float* be_top = (const float*)d_in[10];
    const float* Wg1    = (const float*)d_in[11];
    const float* bg1    = (const float*)d_in[12];
    const float* gg     = (const float*)d_in[13];
    const float* bgb    = (const float*)d_in[14];
    const float* Wg2    = (const float*)d_in[15];
    const float* bg2    = (const float*)d_in[16];

    float* out  = (float*)d_out;
    float* outN = out;                 // gated_ner  [8192][1024] (used as pre-LN scratch first)
    float* outT = out + 8388608;       // gated_topic

    char* ws = (char*)d_ws;
    unsigned short* combined = (unsigned short*)ws;            // [8192][2048] bf16, 32MB
    float*          preln2   = (float*)(ws + 33554432);        // [8192][1024] f32, 32MB
    unsigned short* hbuf     = (unsigned short*)(ws + 67108864); // [8192][1024] bf16, 16MB

    dim3 gdim(8, 64);  // N/128, M/128

    // shared transforms (pre-LN GEMM straight into d_out regions)
    gemm_bias<0><<<gdim, 256, 0, stream>>>(ner, W_ner, b_ner, outN, 8192, 1024, 768, nullptr, 0, 0);
    gemm_bias<0><<<gdim, 256, 0, stream>>>(top, W_top, b_top, outT, 8192, 1024, 768, nullptr, 0, 0);
    ln_relu<<<8192, 256, 0, stream>>>(outN, outN, combined, 2048, 0,    g_ner, be_ner, nullptr);
    ln_relu<<<8192, 256, 0, stream>>>(outT, outT, combined, 2048, 1024, g_top, be_top, nullptr);

    // gate MLP, only the selected language per batch (mathematically identical to masked sum)
    gemm_bias<1><<<gdim, 256, 0, stream>>>(combined, Wg1, bg1, preln2, 8192, 1024, 2048,
                                           lang, 2048l * 1024l, 1024);
    ln_relu<<<8192, 256, 0, stream>>>(preln2, nullptr, hbuf, 1024, 0, gg, bgb, lang);

    // gates + in-place scaling of both output halves
    gate_scale<<<8192, 256, 0, stream>>>(hbuf, Wg2, bg2, lang, out);
}

// Round 2
// 180.779 us; speedup vs baseline: 1.5289x; 1.5289x over previous
//
#include <hip/hip_runtime.h>

typedef __attribute__((ext_vector_type(8))) short short8;
typedef __attribute__((ext_vector_type(4))) float f32x4;

__device__ __forceinline__ float bf2f(unsigned short u) {
    union { unsigned int i; float f; } v; v.i = ((unsigned int)u) << 16; return v.f;
}
__device__ __forceinline__ unsigned short f2bf(float f) {
    union { float f; unsigned int i; } v; v.f = f;
    unsigned int r = v.i + 0x7fffu + ((v.i >> 16) & 1u);  // RNE
    return (unsigned short)(r >> 16);
}

__device__ __forceinline__ void gload16(const unsigned short* g, unsigned short* l) {
    __builtin_amdgcn_global_load_lds(
        (const __attribute__((address_space(1))) unsigned int*)g,
        (__attribute__((address_space(3))) unsigned int*)l, 16, 0, 0);
}

#define BM 128
#define BN 128
#define BK 64

// C[M][1024] = A[M][K](bf16) * Bt[N][K]^T (bf16) + bias, f32 out. m97 structure.
template<int K>
__global__ __launch_bounds__(256) void gemm_bt(
    const unsigned short* __restrict__ A,
    const unsigned short* __restrict__ Btg,
    const float* __restrict__ biasg,
    float* __restrict__ C,
    const int* __restrict__ lang, long Bstride, int biasStride)
{
    constexpr int N = 1024;
    __shared__ __align__(16) unsigned short As[BM][BK];
    __shared__ __align__(16) unsigned short Bs[BN][BK];

    const int t = threadIdx.x;
    // bijective XCD swizzle (nwg = 512, multiple of 8)
    const int nx = gridDim.x;                       // 8
    const int bid = blockIdx.y * nx + blockIdx.x;
    const int cpx = (nx * gridDim.y) >> 3;
    const int swz = (bid & 7) * cpx + (bid >> 3);
    const int gm0 = (swz >> 3) * BM;
    const int gn0 = (swz & 7) * BN;

    const unsigned short* Bt = Btg;
    const float* bias = biasg;
    if (lang) {
        const int l = lang[gm0 >> 9];               // 512 rows per batch, 128 | 512
        Bt += (long)l * Bstride;
        bias += (long)l * biasStride;
    }

    const int lane = t & 63;
    const int w = t >> 6;
    const int wm = w >> 1, wn = w & 1;              // 2x2 waves, 64x64 each
    const int fr = lane & 15;
    const int kq8 = (lane >> 4) * 8;

    // staging geometry: thread t loads 16B; rows of 64 bf16 = 128B; wave-linear LDS dest
    const int srow = t >> 3;                        // 0..31
    const int scol = (t & 7) * 8;                   // bf16 col

    const unsigned short* ag = A  + (size_t)(gm0 + srow) * K + scol;
    const unsigned short* bg = Bt + (size_t)(gn0 + srow) * K + scol;

    f32x4 acc[4][4];
#pragma unroll
    for (int m = 0; m < 4; ++m)
#pragma unroll
        for (int n = 0; n < 4; ++n)
            acc[m][n] = (f32x4){0.f, 0.f, 0.f, 0.f};

    for (int k0 = 0; k0 < K; k0 += BK) {
#pragma unroll
        for (int i = 0; i < 4; ++i) {
            gload16(ag + (size_t)(i * 32) * K + k0, &As[i * 32 + srow][scol]);
            gload16(bg + (size_t)(i * 32) * K + k0, &Bs[i * 32 + srow][scol]);
        }
        __syncthreads();   // drains vmcnt(0) before barrier (compiler-inserted)

        short8 af[2][4], bfv[2][4];
#pragma unroll
        for (int kk = 0; kk < 2; ++kk) {
#pragma unroll
            for (int m = 0; m < 4; ++m) af[kk][m]  = *(const short8*)&As[wm * 64 + m * 16 + fr][kk * 32 + kq8];
#pragma unroll
            for (int n = 0; n < 4; ++n) bfv[kk][n] = *(const short8*)&Bs[wn * 64 + n * 16 + fr][kk * 32 + kq8];
        }
#pragma unroll
        for (int kk = 0; kk < 2; ++kk)
#pragma unroll
            for (int m = 0; m < 4; ++m)
#pragma unroll
                for (int n = 0; n < 4; ++n)
                    acc[m][n] = __builtin_amdgcn_mfma_f32_16x16x32_bf16(af[kk][m], bfv[kk][n], acc[m][n], 0, 0, 0);
        __syncthreads();
    }

    // D mapping: col=lane&15, row=(lane>>4)*4+reg
    const int fq = lane >> 4;
#pragma unroll
    for (int n = 0; n < 4; ++n) {
        const int col = gn0 + wn * 64 + n * 16 + fr;
        const float bv = bias[col];
#pragma unroll
        for (int m = 0; m < 4; ++m) {
            const int row0 = gm0 + wm * 64 + m * 16 + fq * 4;
#pragma unroll
            for (int r = 0; r < 4; ++r)
                C[(size_t)(row0 + r) * N + col] = acc[m][n][r] + bv;
        }
    }
}

// W [K][N] f32 -> Wt [N][K] bf16 (per blockIdx.z language slab)
__global__ __launch_bounds__(256) void wt_bf16(
    const float* __restrict__ W, unsigned short* __restrict__ Wt, int K, int N)
{
    __shared__ float tile[32][33];
    W  += (size_t)blockIdx.z * K * N;
    Wt += (size_t)blockIdx.z * K * N;
    const int n0 = blockIdx.x * 32, k0 = blockIdx.y * 32;
    const int x = threadIdx.x & 31, y = threadIdx.x >> 5;
#pragma unroll
    for (int i = 0; i < 4; ++i)
        tile[y + 8 * i][x] = W[(size_t)(k0 + y + 8 * i) * N + n0 + x];
    __syncthreads();
#pragma unroll
    for (int i = 0; i < 4; ++i)
        Wt[(size_t)(n0 + y + 8 * i) * K + k0 + x] = f2bf(tile[x][y + 8 * i]);
}

// f32 -> bf16 elementwise, n multiple of 2048
__global__ __launch_bounds__(256) void conv_bf16(
    const float* __restrict__ in, unsigned short* __restrict__ out)
{
    const size_t i = ((size_t)blockIdx.x * 256 + threadIdx.x) * 8;
    const float4 a = ((const float4*)(in + i))[0];
    const float4 b = ((const float4*)(in + i))[1];
    ushort4 u, v;
    u.x = f2bf(a.x); u.y = f2bf(a.y); u.z = f2bf(a.z); u.w = f2bf(a.w);
    v.x = f2bf(b.x); v.y = f2bf(b.y); v.z = f2bf(b.z); v.w = f2bf(b.w);
    *(ushort4*)(out + i)     = u;
    *(ushort4*)(out + i + 4) = v;
}

// Row LayerNorm (1024) + ReLU, f32 in -> bf16 out at [row][bcol..bcol+1023] with pitch
__global__ __launch_bounds__(256) void ln_relu(
    const float* __restrict__ in, unsigned short* __restrict__ outb, int bpitch, int bcol,
    const float* __restrict__ gammag, const float* __restrict__ betag,
    const int* __restrict__ lang)
{
    const int r = blockIdx.x, t = threadIdx.x;
    const float4 v = ((const float4*)(in + (size_t)r * 1024))[t];
    float s1 = v.x + v.y + v.z + v.w;
    float s2 = v.x * v.x + v.y * v.y + v.z * v.z + v.w * v.w;
#pragma unroll
    for (int off = 32; off > 0; off >>= 1) {
        s1 += __shfl_down(s1, off);
        s2 += __shfl_down(s2, off);
    }
    __shared__ float red[8];
    const int wid = t >> 6;
    if ((t & 63) == 0) { red[wid] = s1; red[4 + wid] = s2; }
    __syncthreads();
    s1 = red[0] + red[1] + red[2] + red[3];
    s2 = red[4] + red[5] + red[6] + red[7];
    const float mean = s1 * (1.0f / 1024.0f);
    const float var = fmaxf(s2 * (1.0f / 1024.0f) - mean * mean, 0.0f);
    const float rstd = rsqrtf(var + 1e-5f);
    const float* G = gammag;
    const float* Be = betag;
    if (lang) { const int l = lang[r >> 9]; G += l * 1024; Be += l * 1024; }
    const float4 g  = ((const float4*)G)[t];
    const float4 be = ((const float4*)Be)[t];
    ushort4 h;
    h.x = f2bf(fmaxf((v.x - mean) * rstd * g.x + be.x, 0.0f));
    h.y = f2bf(fmaxf((v.y - mean) * rstd * g.y + be.y, 0.0f));
    h.z = f2bf(fmaxf((v.z - mean) * rstd * g.z + be.z, 0.0f));
    h.w = f2bf(fmaxf((v.w - mean) * rstd * g.w + be.w, 0.0f));
    *(ushort4*)(outb + (size_t)r * bpitch + bcol + t * 4) = h;
}

// gates = sigmoid(h . Wg2[l] + bg2[l]); out halves = combined halves (bf16) * gate
__global__ __launch_bounds__(256) void gate_scale(
    const unsigned short* __restrict__ h, const unsigned short* __restrict__ comb,
    const float* __restrict__ Wg2, const float* __restrict__ bg2,
    const int* __restrict__ lang, float* __restrict__ outN, float* __restrict__ outT)
{
    const int r = blockIdx.x, t = threadIdx.x;
    const int l = lang[r >> 9];
    const ushort4 hv = *(const ushort4*)(h + (size_t)r * 1024 + t * 4);
    const float4* W = (const float4*)(Wg2 + (size_t)l * 2048);
    const float4 wa = W[t * 2], wb = W[t * 2 + 1];
    const float h0 = bf2f(hv.x), h1 = bf2f(hv.y), h2 = bf2f(hv.z), h3 = bf2f(hv.w);
    float d0 = h0 * wa.x + h1 * wa.z + h2 * wb.x + h3 * wb.z;
    float d1 = h0 * wa.y + h1 * wa.w + h2 * wb.y + h3 * wb.w;
#pragma unroll
    for (int off = 32; off > 0; off >>= 1) {
        d0 += __shfl_down(d0, off);
        d1 += __shfl_down(d1, off);
    }
    __shared__ float red[8];
    const int wid = t >> 6;
    if ((t & 63) == 0) { red[wid] = d0; red[4 + wid] = d1; }
    __syncthreads();
    d0 = red[0] + red[1] + red[2] + red[3] + bg2[l * 2 + 0];
    d1 = red[4] + red[5] + red[6] + red[7] + bg2[l * 2 + 1];
    const float g0 = 1.0f / (1.0f + __expf(-d0));
    const float g1 = 1.0f / (1.0f + __expf(-d1));
    const ushort4 cn = *(const ushort4*)(comb + (size_t)r * 2048 + t * 4);
    const ushort4 ct = *(const ushort4*)(comb + (size_t)r * 2048 + 1024 + t * 4);
    float4 a, b;
    a.x = bf2f(cn.x) * g0; a.y = bf2f(cn.y) * g0; a.z = bf2f(cn.z) * g0; a.w = bf2f(cn.w) * g0;
    b.x = bf2f(ct.x) * g1; b.y = bf2f(ct.y) * g1; b.z = bf2f(ct.z) * g1; b.w = bf2f(ct.w) * g1;
    ((float4*)(outN + (size_t)r * 1024))[t] = a;
    ((float4*)(outT + (size_t)r * 1024))[t] = b;
}

extern "C" void kernel_launch(void* const* d_in, const int* in_sizes, int n_in,
                              void* d_out, int out_size, void* d_ws, size_t ws_size,
                              hipStream_t stream)
{
    const float* ner    = (const float*)d_in[0];
    const float* top    = (const float*)d_in[1];
    const int*   lang   = (const int*)d_in[2];
    const float* W_ner  = (const float*)d_in[3];
    const float* b_ner  = (const float*)d_in[4];
    const float* g_ner  = (const float*)d_in[5];
    const float* be_ner = (const float*)d_in[6];
    const float* W_top  = (const float*)d_in[7];
    const float* b_top  = (const float*)d_in[8];
    const float* g_top  = (const float*)d_in[9];
    const float* be_top = (const float*)d_in[10];
    const float* Wg1    = (const float*)d_in[11];
    const float* bg1    = (const float*)d_in[12];
    const float* gg     = (const float*)d_in[13];
    const float* bgb    = (const float*)d_in[14];
    const float* Wg2    = (const float*)d_in[15];
    const float* bg2    = (const float*)d_in[16];

    float* out  = (float*)d_out;
    float* outN = out;             // final gated_ner; also pre-LN f32 scratch
    float* outT = out + 8388608;   // final gated_topic; also scratch

    // ws layout (~71 MB)
    char* ws = (char*)d_ws;
    unsigned short* combined = (unsigned short*)ws;                   // [8192][2048] bf16, 32MB
    unsigned short* topb     = (unsigned short*)(ws + 33554432);      // [8192][768] bf16 (dead after GEMM1b)
    unsigned short* hbuf     = (unsigned short*)(ws + 33554432);      // [8192][1024] bf16 (overlays topb)
    unsigned short* W_nert   = (unsigned short*)(ws + 50331648);      // [1024][768]
    unsigned short* W_topt   = (unsigned short*)(ws + 51904512);      // [1024][768]
    unsigned short* Wg1t     = (unsigned short*)(ws + 53477376);      // [5][1024][2048]
    // nerb lives in the outT half of d_out until GEMM1b overwrites it
    unsigned short* nerb     = (unsigned short*)outT;                 // [8192][768] bf16

    const dim3 gdim(8, 64);  // N/128, M/128 -> 512 blocks

    // weight prep (bf16, [N][K])
    wt_bf16<<<dim3(32, 24, 1), 256, 0, stream>>>(W_ner, W_nert, 768, 1024);
    wt_bf16<<<dim3(32, 24, 1), 256, 0, stream>>>(W_top, W_topt, 768, 1024);
    wt_bf16<<<dim3(32, 64, 5), 256, 0, stream>>>(Wg1, Wg1t, 2048, 1024);

    // ner branch: conv -> GEMM (pre-LN f32 into outN) -> LN+ReLU -> combined[:, :1024]
    conv_bf16<<<3072, 256, 0, stream>>>(ner, nerb);
    gemm_bt<768><<<gdim, 256, 0, stream>>>(nerb, W_nert, b_ner, outN, nullptr, 0, 0);
    ln_relu<<<8192, 256, 0, stream>>>(outN, combined, 2048, 0, g_ner, be_ner, nullptr);

    // topic branch (topb in ws; GEMM1b overwrites nerb's region with its output)
    conv_bf16<<<3072, 256, 0, stream>>>(top, topb);
    gemm_bt<768><<<gdim, 256, 0, stream>>>(topb, W_topt, b_top, outT, nullptr, 0, 0);
    ln_relu<<<8192, 256, 0, stream>>>(outT, combined, 2048, 1024, g_top, be_top, nullptr);

    // gate MLP (selected language only), pre-LN f32 into outN
    gemm_bt<2048><<<gdim, 256, 0, stream>>>(combined, Wg1t, bg1, outN,
                                            lang, 2048l * 1024l, 1024);
    ln_relu<<<8192, 256, 0, stream>>>(outN, hbuf, 1024, 0, gg, bgb, lang);

    // gates + final scaled outputs (reads bf16 combined, writes f32 outputs)
    gate_scale<<<8192, 256, 0, stream>>>(hbuf, combined, Wg2, bg2, lang, outN, outT);
}

// Round 3
// 149.832 us; speedup vs baseline: 1.8447x; 1.2065x over previous
//
#include <hip/hip_runtime.h>

typedef __attribute__((ext_vector_type(8))) short short8;
typedef __attribute__((ext_vector_type(4))) float f32x4;

__device__ __forceinline__ float bf2f(unsigned short u) {
    union { unsigned int i; float f; } v; v.i = ((unsigned int)u) << 16; return v.f;
}
__device__ __forceinline__ unsigned short f2bf(float f) {
    union { float f; unsigned int i; } v; v.f = f;
    unsigned int r = v.i + 0x7fffu + ((v.i >> 16) & 1u);  // RNE
    return (unsigned short)(r >> 16);
}
__device__ __forceinline__ void gload16(const unsigned short* g, unsigned short* l) {
    __builtin_amdgcn_global_load_lds(
        (const __attribute__((address_space(1))) unsigned int*)g,
        (__attribute__((address_space(3))) unsigned int*)l, 16, 0, 0);
}

// ---------------------------------------------------------------------------
// GEMM: C[M][1024](bf16) = A[M][K](bf16) @ Bt[1024][K]^T (bf16) + bias
// 128x128 tile, BK=64, 4 waves, 2-deep counted-vmcnt pipeline, T2 swizzle.
// MODE 0: M=16384 merged (rows<8192 -> Bta/biasa -> cols 0..1023 of combined;
//         rows>=8192 -> Btb/biasb -> cols 1024..2047), pitch 2048.
// MODE 1: per-batch language select from Bta stack, pitch 1024.
// ---------------------------------------------------------------------------
template<int K, int MODE>
__global__ __launch_bounds__(256) void gemm_p2(
    const unsigned short* __restrict__ A,
    const unsigned short* __restrict__ Bta,
    const unsigned short* __restrict__ Btb,
    const float* __restrict__ biasa,
    const float* __restrict__ biasb,
    unsigned short* __restrict__ Cb,
    const int* __restrict__ lang)
{
    __shared__ __align__(16) unsigned short As0[128][64], Bs0[128][64];
    __shared__ __align__(16) unsigned short As1[128][64], Bs1[128][64];

    const int t = threadIdx.x;
    // bijective XCD swizzle (nwg multiple of 8)
    const int nwg = gridDim.x * gridDim.y;
    const int bid = blockIdx.y * gridDim.x + blockIdx.x;
    const int swz = (bid & 7) * (nwg >> 3) + (bid >> 3);
    const int gm0 = (swz >> 3) * 128;
    const int gn0 = (swz & 7) * 128;

    const unsigned short* Bt;
    const float* bias;
    int sel = 0;
    if (MODE == 0) {
        sel = gm0 >> 13;
        Bt = sel ? Btb : Bta;
        bias = sel ? biasb : biasa;
    } else {
        const int l = lang[gm0 >> 9];
        Bt = Bta + (size_t)l * (K * 1024);
        bias = biasa + l * 1024;
    }

    const int lane = t & 63;
    const int w = t >> 6, wm = w >> 1, wn = w & 1;     // 2x2 waves, 64x64 each
    const int fr = lane & 15, g4 = lane >> 4, f7 = lane & 7;
    // swizzled fragment columns (16B-slot index XOR row&7), element units
    const int csw0 = ((0 + g4) ^ f7) * 8;
    const int csw1 = ((4 + g4) ^ f7) * 8;

    // staging: thread t -> LDS row srow(+i*32), linear dest col; swizzled global col
    const int srow = t >> 3;
    const int swcol = ((t & 7) ^ (srow & 7)) * 8;
    const int lcol = (t & 7) * 8;
    const unsigned short* ag = A  + (size_t)(gm0 + srow) * K + swcol;
    const unsigned short* bg = Bt + (size_t)(gn0 + srow) * K + swcol;

    f32x4 acc[4][4];
#pragma unroll
    for (int m = 0; m < 4; ++m)
#pragma unroll
        for (int n = 0; n < 4; ++n)
            acc[m][n] = (f32x4){0.f, 0.f, 0.f, 0.f};

    auto stage = [&](unsigned short (*As)[64], unsigned short (*Bs)[64], int k0) {
#pragma unroll
        for (int i = 0; i < 4; ++i) {
            gload16(ag + (size_t)(i * 32) * K + k0, &As[i * 32 + srow][lcol]);
            gload16(bg + (size_t)(i * 32) * K + k0, &Bs[i * 32 + srow][lcol]);
        }
    };
    auto compute = [&](const unsigned short (*As)[64], const unsigned short (*Bs)[64]) {
        short8 a0[4], b0[4];
#pragma unroll
        for (int m = 0; m < 4; ++m) a0[m] = *(const short8*)&As[wm * 64 + m * 16 + fr][csw0];
#pragma unroll
        for (int n = 0; n < 4; ++n) b0[n] = *(const short8*)&Bs[wn * 64 + n * 16 + fr][csw0];
#pragma unroll
        for (int m = 0; m < 4; ++m)
#pragma unroll
            for (int n = 0; n < 4; ++n)
                acc[m][n] = __builtin_amdgcn_mfma_f32_16x16x32_bf16(a0[m], b0[n], acc[m][n], 0, 0, 0);
#pragma unroll
        for (int m = 0; m < 4; ++m) a0[m] = *(const short8*)&As[wm * 64 + m * 16 + fr][csw1];
#pragma unroll
        for (int n = 0; n < 4; ++n) b0[n] = *(const short8*)&Bs[wn * 64 + n * 16 + fr][csw1];
#pragma unroll
        for (int m = 0; m < 4; ++m)
#pragma unroll
            for (int n = 0; n < 4; ++n)
                acc[m][n] = __builtin_amdgcn_mfma_f32_16x16x32_bf16(a0[m], b0[n], acc[m][n], 0, 0, 0);
    };

    constexpr int NT = K / 64;           // even (12 or 32)
    stage(As0, Bs0, 0);
    stage(As1, Bs1, 64);

    for (int tt = 0; tt < NT; tt += 2) {
        // ---- even tile (As0/Bs0): tiles tt, tt+1 in flight (16 loads) ----
        asm volatile("s_waitcnt vmcnt(8)" ::: "memory");   // tile tt landed
        __builtin_amdgcn_s_barrier();
        asm volatile("" ::: "memory");
        __builtin_amdgcn_sched_barrier(0);
        compute(As0, Bs0);
        __builtin_amdgcn_sched_barrier(0);
        __builtin_amdgcn_s_barrier();                      // all waves done reading As0/Bs0
        if (tt + 2 < NT) stage(As0, Bs0, (tt + 2) * 64);
        // ---- odd tile (As1/Bs1) ----
        if (tt + 2 < NT) asm volatile("s_waitcnt vmcnt(8)" ::: "memory");
        else             asm volatile("s_waitcnt vmcnt(0)" ::: "memory");
        __builtin_amdgcn_s_barrier();
        asm volatile("" ::: "memory");
        __builtin_amdgcn_sched_barrier(0);
        compute(As1, Bs1);
        __builtin_amdgcn_sched_barrier(0);
        __builtin_amdgcn_s_barrier();
        if (tt + 3 < NT) stage(As1, Bs1, (tt + 3) * 64);
    }

    // epilogue: D mapping col=lane&15, row=(lane>>4)*4+reg; bf16 store
    const int fq = lane >> 4;
    const size_t pitch  = (MODE == 0) ? 2048 : 1024;
    const size_t coloff = (MODE == 0) ? (size_t)sel * 1024 : 0;
    const int rbase = (MODE == 0) ? (gm0 & 8191) : gm0;
#pragma unroll
    for (int n = 0; n < 4; ++n) {
        const int col = gn0 + wn * 64 + n * 16 + fr;
        const float bv = bias[col];
#pragma unroll
        for (int m = 0; m < 4; ++m) {
            const int row0 = rbase + wm * 64 + m * 16 + fq * 4;
#pragma unroll
            for (int r = 0; r < 4; ++r)
                Cb[(size_t)(row0 + r) * pitch + coloff + col] = f2bf(acc[m][n][r] + bv);
        }
    }
}

// W [K][N] f32 -> Wt [N][K] bf16 (per blockIdx.z slab)
__global__ __launch_bounds__(256) void wt_bf16(
    const float* __restrict__ W, unsigned short* __restrict__ Wt, int K, int N)
{
    __shared__ float tile[32][33];
    W  += (size_t)blockIdx.z * K * N;
    Wt += (size_t)blockIdx.z * K * N;
    const int n0 = blockIdx.x * 32, k0 = blockIdx.y * 32;
    const int x = threadIdx.x & 31, y = threadIdx.x >> 5;
#pragma unroll
    for (int i = 0; i < 4; ++i)
        tile[y + 8 * i][x] = W[(size_t)(k0 + y + 8 * i) * N + n0 + x];
    __syncthreads();
#pragma unroll
    for (int i = 0; i < 4; ++i)
        Wt[(size_t)(n0 + y + 8 * i) * K + k0 + x] = f2bf(tile[x][y + 8 * i]);
}

// f32 -> bf16 elementwise (2048 elems / block)
__global__ __launch_bounds__(256) void conv_bf16(
    const float* __restrict__ in, unsigned short* __restrict__ out)
{
    const size_t i = ((size_t)blockIdx.x * 256 + threadIdx.x) * 8;
    const float4 a = ((const float4*)(in + i))[0];
    const float4 b = ((const float4*)(in + i))[1];
    ushort4 u, v;
    u.x = f2bf(a.x); u.y = f2bf(a.y); u.z = f2bf(a.z); u.w = f2bf(a.w);
    v.x = f2bf(b.x); v.y = f2bf(b.y); v.z = f2bf(b.z); v.w = f2bf(b.w);
    *(ushort4*)(out + i)     = u;
    *(ushort4*)(out + i + 4) = v;
}

// in-place LN(1024)+ReLU on combined halves (bf16). grid 16384: r=b>>1, half=b&1
__global__ __launch_bounds__(256) void ln_relu_c(
    unsigned short* __restrict__ comb,
    const float* __restrict__ gn, const float* __restrict__ bn,
    const float* __restrict__ gt, const float* __restrict__ btp)
{
    const int b = blockIdx.x, t = threadIdx.x;
    const int r = b >> 1, half = b & 1;
    unsigned short* p = comb + (size_t)r * 2048 + half * 1024 + t * 4;
    ushort4 u = *(const ushort4*)p;
    const float x0 = bf2f(u.x), x1 = bf2f(u.y), x2 = bf2f(u.z), x3 = bf2f(u.w);
    float s1 = x0 + x1 + x2 + x3;
    float s2 = x0 * x0 + x1 * x1 + x2 * x2 + x3 * x3;
#pragma unroll
    for (int off = 32; off > 0; off >>= 1) {
        s1 += __shfl_down(s1, off);
        s2 += __shfl_down(s2, off);
    }
    __shared__ float red[8];
    const int wid = t >> 6;
    if ((t & 63) == 0) { red[wid] = s1; red[4 + wid] = s2; }
    __syncthreads();
    s1 = red[0] + red[1] + red[2] + red[3];
    s2 = red[4] + red[5] + red[6] + red[7];
    const float mean = s1 * (1.0f / 1024.0f);
    const float var = fmaxf(s2 * (1.0f / 1024.0f) - mean * mean, 0.0f);
    const float rstd = rsqrtf(var + 1e-5f);
    const float* G  = half ? gt : gn;
    const float* Be = half ? btp : bn;
    const float4 g  = ((const float4*)G)[t];
    const float4 be = ((const float4*)Be)[t];
    u.x = f2bf(fmaxf((x0 - mean) * rstd * g.x + be.x, 0.0f));
    u.y = f2bf(fmaxf((x1 - mean) * rstd * g.y + be.y, 0.0f));
    u.z = f2bf(fmaxf((x2 - mean) * rstd * g.z + be.z, 0.0f));
    u.w = f2bf(fmaxf((x3 - mean) * rstd * g.w + be.w, 0.0f));
    *(ushort4*)p = u;
}

// LN(1024)+ReLU, bf16 in -> bf16 out, language-selected gamma/beta
__global__ __launch_bounds__(256) void ln_relu_l(
    const unsigned short* __restrict__ in, unsigned short* __restrict__ out,
    const float* __restrict__ gg, const float* __restrict__ bg,
    const int* __restrict__ lang)
{
    const int r = blockIdx.x, t = threadIdx.x;
    const ushort4 u = *(const ushort4*)(in + (size_t)r * 1024 + t * 4);
    const float x0 = bf2f(u.x), x1 = bf2f(u.y), x2 = bf2f(u.z), x3 = bf2f(u.w);
    float s1 = x0 + x1 + x2 + x3;
    float s2 = x0 * x0 + x1 * x1 + x2 * x2 + x3 * x3;
#pragma unroll
    for (int off = 32; off > 0; off >>= 1) {
        s1 += __shfl_down(s1, off);
        s2 += __shfl_down(s2, off);
    }
    __shared__ float red[8];
    const int wid = t >> 6;
    if ((t & 63) == 0) { red[wid] = s1; red[4 + wid] = s2; }
    __syncthreads();
    s1 = red[0] + red[1] + red[2] + red[3];
    s2 = red[4] + red[5] + red[6] + red[7];
    const float mean = s1 * (1.0f / 1024.0f);
    const float var = fmaxf(s2 * (1.0f / 1024.0f) - mean * mean, 0.0f);
    const float rstd = rsqrtf(var + 1e-5f);
    const int l = lang[r >> 9];
    const float4 g  = ((const float4*)(gg + l * 1024))[t];
    const float4 be = ((const float4*)(bg + l * 1024))[t];
    ushort4 h;
    h.x = f2bf(fmaxf((x0 - mean) * rstd * g.x + be.x, 0.0f));
    h.y = f2bf(fmaxf((x1 - mean) * rstd * g.y + be.y, 0.0f));
    h.z = f2bf(fmaxf((x2 - mean) * rstd * g.z + be.z, 0.0f));
    h.w = f2bf(fmaxf((x3 - mean) * rstd * g.w + be.w, 0.0f));
    *(ushort4*)(out + (size_t)r * 1024 + t * 4) = h;
}

// gates = sigmoid(h . Wg2[l] + bg2[l]); outputs = combined halves (bf16) * gate, f32
__global__ __launch_bounds__(256) void gate_scale(
    const unsigned short* __restrict__ h, const unsigned short* __restrict__ comb,
    const float* __restrict__ Wg2, const float* __restrict__ bg2,
    const int* __restrict__ lang, float* __restrict__ outN, float* __restrict__ outT)
{
    const int r = blockIdx.x, t = threadIdx.x;
    const int l = lang[r >> 9];
    const ushort4 hv = *(const ushort4*)(h + (size_t)r * 1024 + t * 4);
    const float4* W = (const float4*)(Wg2 + (size_t)l * 2048);
    const float4 wa = W[t * 2], wb = W[t * 2 + 1];
    const float h0 = bf2f(hv.x), h1 = bf2f(hv.y), h2 = bf2f(hv.z), h3 = bf2f(hv.w);
    float d0 = h0 * wa.x + h1 * wa.z + h2 * wb.x + h3 * wb.z;
    float d1 = h0 * wa.y + h1 * wa.w + h2 * wb.y + h3 * wb.w;
#pragma unroll
    for (int off = 32; off > 0; off >>= 1) {
        d0 += __shfl_down(d0, off);
        d1 += __shfl_down(d1, off);
    }
    __shared__ float red[8];
    const int wid = t >> 6;
    if ((t & 63) == 0) { red[wid] = d0; red[4 + wid] = d1; }
    __syncthreads();
    d0 = red[0] + red[1] + red[2] + red[3] + bg2[l * 2 + 0];
    d1 = red[4] + red[5] + red[6] + red[7] + bg2[l * 2 + 1];
    const float g0 = 1.0f / (1.0f + __expf(-d0));
    const float g1 = 1.0f / (1.0f + __expf(-d1));
    const ushort4 cn = *(const ushort4*)(comb + (size_t)r * 2048 + t * 4);
    const ushort4 ct = *(const ushort4*)(comb + (size_t)r * 2048 + 1024 + t * 4);
    float4 a, b;
    a.x = bf2f(cn.x) * g0; a.y = bf2f(cn.y) * g0; a.z = bf2f(cn.z) * g0; a.w = bf2f(cn.w) * g0;
    b.x = bf2f(ct.x) * g1; b.y = bf2f(ct.y) * g1; b.z = bf2f(ct.z) * g1; b.w = bf2f(ct.w) * g1;
    ((float4*)(outN + (size_t)r * 1024))[t] = a;
    ((float4*)(outT + (size_t)r * 1024))[t] = b;
}

extern "C" void kernel_launch(void* const* d_in, const int* in_sizes, int n_in,
                              void* d_out, int out_size, void* d_ws, size_t ws_size,
                              hipStream_t stream)
{
    const float* ner    = (const float*)d_in[0];
    const float* top    = (const float*)d_in[1];
    const int*   lang   = (const int*)d_in[2];
    const float* W_ner  = (const float*)d_in[3];
    const float* b_ner  = (const float*)d_in[4];
    const float* g_ner  = (const float*)d_in[5];
    const float* be_ner = (const float*)d_in[6];
    const float* W_top  = (const float*)d_in[7];
    const float* b_top  = (const float*)d_in[8];
    const float* g_top  = (const float*)d_in[9];
    const float* be_top = (const float*)d_in[10];
    const float* Wg1    = (const float*)d_in[11];
    const float* bg1    = (const float*)d_in[12];
    const float* gg     = (const float*)d_in[13];
    const float* bgb    = (const float*)d_in[14];
    const float* Wg2    = (const float*)d_in[15];
    const float* bg2    = (const float*)d_in[16];

    float* out  = (float*)d_out;
    float* outN = out;             // final gated_ner; preln2 scratch before that
    float* outT = out + 8388608;   // final gated_topic; weight-transpose scratch before

    // scratch layout
    char* ws = (char*)d_ws;
    unsigned short* combined = (unsigned short*)ws;                 // [8192][2048] bf16, 32MB
    unsigned short* actb     = (unsigned short*)(ws + 33554432);    // [16384][768] bf16, 24MB
    unsigned short* hbuf     = (unsigned short*)(ws + 33554432);    // [8192][1024] overlays actb (dead)
    unsigned short* Wg1t     = (unsigned short*)(ws + 58720256);    // [5][1024][2048] bf16, 20MB
    unsigned short* W_nert   = (unsigned short*)outT;               // [1024][768] bf16 (d_out scratch)
    unsigned short* W_topt   = W_nert + 786432;                     // [1024][768]
    unsigned short* preln2   = (unsigned short*)outN;               // [8192][1024] bf16 (d_out scratch)

    // weight prep: f32 [K][N] -> bf16 [N][K]
    wt_bf16<<<dim3(32, 24, 1), 256, 0, stream>>>(W_ner, W_nert, 768, 1024);
    wt_bf16<<<dim3(32, 24, 1), 256, 0, stream>>>(W_top, W_topt, 768, 1024);
    wt_bf16<<<dim3(32, 64, 5), 256, 0, stream>>>(Wg1, Wg1t, 2048, 1024);

    // activations f32 -> bf16, concatenated on M
    conv_bf16<<<3072, 256, 0, stream>>>(ner, actb);
    conv_bf16<<<3072, 256, 0, stream>>>(top, actb + 6291456);

    // merged shared-transform GEMM: [16384][768] -> combined pre-LN (bf16)
    gemm_p2<768, 0><<<dim3(8, 128), 256, 0, stream>>>(
        actb, W_nert, W_topt, b_ner, b_top, combined, nullptr);
    // LN+ReLU in-place on both halves of combined
    ln_relu_c<<<16384, 256, 0, stream>>>(combined, g_ner, be_ner, g_top, be_top);

    // gate MLP first layer (language-selected), pre-LN bf16 into d_out scratch
    gemm_p2<2048, 1><<<dim3(8, 64), 256, 0, stream>>>(
        combined, Wg1t, nullptr, bg1, nullptr, preln2, lang);
    ln_relu_l<<<8192, 256, 0, stream>>>(preln2, hbuf, gg, bgb, lang);

    // gates + final outputs (overwrites all d_out scratch)
    gate_scale<<<8192, 256, 0, stream>>>(hbuf, combined, Wg2, bg2, lang, outN, outT);
}